// Round 1
// baseline (634.960 us; speedup 1.0000x reference)
//
#include <hip/hip_runtime.h>
#include <hip/hip_bf16.h>
#include <math.h>

#define N_WIRES 12
#define DIM     4096
#define BATCH   128
#define BM      128
#define BN      64
#define BK      64
#define KSPLIT  4
#define KCHUNK  (DIM / KSPLIT)

typedef __attribute__((ext_vector_type(4))) float f32x4;
typedef __attribute__((ext_vector_type(4))) unsigned int u32x4;
typedef __bf16 bf16x8 __attribute__((ext_vector_type(8)));

__device__ __forceinline__ f32x4 mfma16(bf16x8 a, bf16x8 b, f32x4 c){
  return __builtin_amdgcn_mfma_f32_16x16x32_bf16(a, b, c, 0, 0, 0);
}

// ---------------------------------------------------------------- normalize
__global__ void k_normalize(const float* __restrict__ x, float* __restrict__ dst){
  const int b = blockIdx.x, t = threadIdx.x;
  const float4* xr = reinterpret_cast<const float4*>(x + (size_t)b * DIM);
  float4 v[4];
  float ss = 0.f;
  #pragma unroll
  for (int r = 0; r < 4; ++r){
    v[r] = xr[t + r*256];
    ss += v[r].x*v[r].x + v[r].y*v[r].y + v[r].z*v[r].z + v[r].w*v[r].w;
  }
  #pragma unroll
  for (int off = 32; off > 0; off >>= 1) ss += __shfl_down(ss, off);
  __shared__ float sred[4];
  if ((t & 63) == 0) sred[t >> 6] = ss;
  __syncthreads();
  const float inv = 1.f / sqrtf(sred[0] + sred[1] + sred[2] + sred[3]);
  float4* dre = reinterpret_cast<float4*>(dst + (size_t)b * DIM);
  float4* dimp = reinterpret_cast<float4*>(dst + (size_t)BATCH*DIM + (size_t)b * DIM);
  const float4 z4 = make_float4(0.f, 0.f, 0.f, 0.f);
  #pragma unroll
  for (int r = 0; r < 4; ++r){
    float4 o; o.x=v[r].x*inv; o.y=v[r].y*inv; o.z=v[r].z*inv; o.w=v[r].w*inv;
    dre[t + r*256]  = o;
    dimp[t + r*256] = z4;
  }
}

// ---------------------------------------------------------------- complex GEMM
// C[b,n] = sum_k U[n,k] * X[b,k]   (complex), split over K into KSPLIT partials.
// X layout: [2][BATCH][DIM] f32 (re, im).  P layout: [KSPLIT][2][BATCH][DIM] f32.
__global__ __launch_bounds__(256) void k_gemm(
    const float* __restrict__ Ure, const float* __restrict__ Uim,
    const float* __restrict__ X, float* __restrict__ P)
{
  __shared__ __bf16 Xs[2*BM*BK];   // [c][row][k] swizzled, 32 KB
  __shared__ __bf16 Us[2*BN*BK];   // [c][n][k]  swizzled, 16 KB
  const int t = threadIdx.x;
  const int lane = t & 63, wid = t >> 6;
  const int n0 = blockIdx.x * BN;
  const int kb = blockIdx.y * KCHUNK;

  const f32x4 z4 = {0.f, 0.f, 0.f, 0.f};
  f32x4 acc_re[2][4], acc_im[2][4];
  #pragma unroll
  for (int mi = 0; mi < 2; ++mi)
    #pragma unroll
    for (int ni = 0; ni < 4; ++ni){ acc_re[mi][ni] = z4; acc_im[mi][ni] = z4; }

  for (int kk = 0; kk < KCHUNK; kk += BK){
    __syncthreads();
    #pragma unroll
    for (int c = 0; c < 2; ++c){
      const float* src = X + (size_t)c*BATCH*DIM;
      #pragma unroll
      for (int r = 0; r < 8; ++r){
        const int idx = r*256 + t;            // 0..2047
        const int row = idx >> 4, q = idx & 15;
        const float4 v = *reinterpret_cast<const float4*>(src + (size_t)row*DIM + kb + kk + q*4);
        union { __bf16 h[4]; unsigned long long u; } pk;
        pk.h[0]=(__bf16)v.x; pk.h[1]=(__bf16)v.y; pk.h[2]=(__bf16)v.z; pk.h[3]=(__bf16)v.w;
        const int off = c*BM*BK + row*BK + ((q*4) ^ ((row & 7) << 3));
        *reinterpret_cast<unsigned long long*>(&Xs[off]) = pk.u;
      }
      const float* us = c ? Uim : Ure;
      #pragma unroll
      for (int r = 0; r < 4; ++r){
        const int idx = r*256 + t;            // 0..1023
        const int row = idx >> 4, q = idx & 15;
        const float4 v = *reinterpret_cast<const float4*>(us + (size_t)(n0+row)*DIM + kb + kk + q*4);
        union { __bf16 h[4]; unsigned long long u; } pk;
        pk.h[0]=(__bf16)v.x; pk.h[1]=(__bf16)v.y; pk.h[2]=(__bf16)v.z; pk.h[3]=(__bf16)v.w;
        const int off = c*BN*BK + row*BK + ((q*4) ^ ((row & 7) << 3));
        *reinterpret_cast<unsigned long long*>(&Us[off]) = pk.u;
      }
    }
    __syncthreads();
    #pragma unroll
    for (int ks = 0; ks < 2; ++ks){
      const int kf = ks*32 + ((lane >> 4) << 3);
      bf16x8 afr[2][2], bfr[2][4], an[2];
      #pragma unroll
      for (int mi = 0; mi < 2; ++mi){
        const int row = wid*32 + mi*16 + (lane & 15);
        const int sw = row*BK + (kf ^ ((row & 7) << 3));
        afr[0][mi] = *reinterpret_cast<const bf16x8*>(&Xs[sw]);
        afr[1][mi] = *reinterpret_cast<const bf16x8*>(&Xs[BM*BK + sw]);
      }
      #pragma unroll
      for (int ni = 0; ni < 4; ++ni){
        const int row = ni*16 + (lane & 15);
        const int sw = row*BK + (kf ^ ((row & 7) << 3));
        bfr[0][ni] = *reinterpret_cast<const bf16x8*>(&Us[sw]);
        bfr[1][ni] = *reinterpret_cast<const bf16x8*>(&Us[BN*BK + sw]);
      }
      #pragma unroll
      for (int mi = 0; mi < 2; ++mi){
        const u32x4 negu = __builtin_bit_cast(u32x4, afr[1][mi]) ^ 0x80008000u;
        an[mi] = __builtin_bit_cast(bf16x8, negu);
      }
      #pragma unroll
      for (int mi = 0; mi < 2; ++mi)
        #pragma unroll
        for (int ni = 0; ni < 4; ++ni){
          acc_re[mi][ni] = mfma16(afr[0][mi], bfr[0][ni], acc_re[mi][ni]); // +Ure*Xre
          acc_re[mi][ni] = mfma16(an[mi],     bfr[1][ni], acc_re[mi][ni]); // -Uim*Xim
          acc_im[mi][ni] = mfma16(afr[0][mi], bfr[1][ni], acc_im[mi][ni]); // +Uim*Xre
          acc_im[mi][ni] = mfma16(afr[1][mi], bfr[0][ni], acc_im[mi][ni]); // +Ure*Xim
        }
    }
  }
  float* pre = P + (size_t)(blockIdx.y*2 + 0)*BATCH*DIM;
  float* pim = P + (size_t)(blockIdx.y*2 + 1)*BATCH*DIM;
  #pragma unroll
  for (int mi = 0; mi < 2; ++mi)
    #pragma unroll
    for (int ni = 0; ni < 4; ++ni){
      const int col = n0 + ni*16 + (lane & 15);
      const int m0 = wid*32 + mi*16 + (lane >> 4)*4;
      #pragma unroll
      for (int j = 0; j < 4; ++j){
        pre[(size_t)(m0+j)*DIM + col] = acc_re[mi][ni][j];
        pim[(size_t)(m0+j)*DIM + col] = acc_im[mi][ni][j];
      }
    }
}

// ------------------------------------------------- CNOT ring index gather map
// state'[x] = state[src(x)]: apply gate maps g_11 ... g_0 (t ^= c) to x.
__device__ __forceinline__ int cnot_src(int x){
  #pragma unroll
  for (int i = 11; i >= 0; --i){
    const int cb = 11 - i;               // bitpos of control wire i
    const int tb = 11 - ((i + 1) % 12);  // bitpos of target wire i+1
    x ^= ((x >> cb) & 1) << tb;
  }
  return x;
}

// ---------------------------------------------------------------- reduce
// MODE 1: sum partials + CNOT-ring permute -> complex state buffer
// MODE 2: sum partials + abs -> d_out (f32)
template<int MODE>
__global__ void k_reduce(const float* __restrict__ P, float* __restrict__ dst){
  const int idx = blockIdx.x * 256 + threadIdx.x;   // 0..524287
  const int b = idx >> 12;
  const int k = idx & (DIM - 1);
  const int n = (MODE == 1) ? cnot_src(k) : k;
  float re = 0.f, im = 0.f;
  #pragma unroll
  for (int s = 0; s < KSPLIT; ++s){
    re += P[((size_t)(s*2+0)*BATCH + b)*DIM + n];
    im += P[((size_t)(s*2+1)*BATCH + b)*DIM + n];
  }
  if (MODE == 2){
    dst[idx] = sqrtf(re*re + im*im);
  } else {
    dst[(size_t)b*DIM + k] = re;
    dst[(size_t)BATCH*DIM + (size_t)b*DIM + k] = im;
  }
}

// ---------------------------------------------------------------- QFT
// Consumes split-K partials directly (fuses the plain reduce).
// for m = 11..1: H(wire m) then fused diagonal CP phases; finally bit-reversal.
__global__ void k_qft(const float* __restrict__ P, float* __restrict__ out){
  __shared__ float sre[DIM];
  __shared__ float sim[DIM];
  const int b = blockIdx.x, t = threadIdx.x;
  for (int i = t; i < DIM; i += 256){
    float re = 0.f, im = 0.f;
    #pragma unroll
    for (int s = 0; s < KSPLIT; ++s){
      re += P[((size_t)(s*2+0)*BATCH + b)*DIM + i];
      im += P[((size_t)(s*2+1)*BATCH + b)*DIM + i];
    }
    sre[i] = re; sim[i] = im;
  }
  __syncthreads();
  const float rs2 = 0.70710678118654752440f;
  for (int m = 11; m >= 1; --m){
    const int p = 11 - m;        // bit position of wire m (wire 0 = MSB)
    const int mask = 1 << p;
    for (int q = t; q < 2048; q += 256){
      const int i0 = ((q & ~(mask-1)) << 1) | (q & (mask-1));
      const int i1 = i0 | mask;
      const float r0 = sre[i0], s0 = sim[i0], r1 = sre[i1], s1 = sim[i1];
      sre[i0] = (r0 + r1) * rs2; sim[i0] = (s0 + s1) * rs2;
      sre[i1] = (r0 - r1) * rs2; sim[i1] = (s0 - s1) * rs2;
    }
    __syncthreads();
    for (int q = t; q < 2048; q += 256){
      const int i1 = (((q & ~(mask-1)) << 1) | (q & (mask-1))) | mask;
      int u = i1 >> (p + 1);     // higher bits = wires 0..m-1
      float phi = 0.f, w = 1.57079632679489662f;   // pi/2 for wire m-1
      while (u){ if (u & 1) phi += w; w *= 0.5f; u >>= 1; }
      float cc, ss;
      __sincosf(phi, &ss, &cc);
      const float r = sre[i1], q2 = sim[i1];
      sre[i1] = r*cc - q2*ss;
      sim[i1] = r*ss + q2*cc;
    }
    __syncthreads();
  }
  for (int i = t; i < DIM; i += 256){
    const int rsrc = (int)(__brev((unsigned)i) >> 20);   // 12-bit reversal (SWAP net)
    out[(size_t)b*DIM + i] = sre[rsrc];
    out[(size_t)BATCH*DIM + (size_t)b*DIM + i] = sim[rsrc];
  }
}

// ---------------------------------------------------------------- launch
extern "C" void kernel_launch(void* const* d_in, const int* in_sizes, int n_in,
                              void* d_out, int out_size, void* d_ws, size_t ws_size,
                              hipStream_t stream){
  const float* x   = (const float*)d_in[0];
  const float* Ure = (const float*)d_in[1];   // [4][DIM][DIM]
  const float* Uim = (const float*)d_in[2];
  float* out = (float*)d_out;

  float* P  = (float*)d_ws;                               // 16 MB partials
  float* B0 = P  + (size_t)KSPLIT*2*BATCH*DIM;            // 4 MB complex state
  float* B1 = B0 + (size_t)2*BATCH*DIM;                   // 4 MB complex state
  const size_t UST = (size_t)DIM*DIM;

  k_normalize<<<BATCH, 256, 0, stream>>>(x, B0);

  // vqc(0): U0, CNOT ring, U1
  k_gemm<<<dim3(DIM/BN, KSPLIT), 256, 0, stream>>>(Ure, Uim, B0, P);
  k_reduce<1><<<2048, 256, 0, stream>>>(P, B1);
  k_gemm<<<dim3(DIM/BN, KSPLIT), 256, 0, stream>>>(Ure + UST, Uim + UST, B1, P);
  // qft (consumes partials, writes B0)
  k_qft<<<BATCH, 256, 0, stream>>>(P, B0);
  // vqc(1): U2, CNOT ring, U3
  k_gemm<<<dim3(DIM/BN, KSPLIT), 256, 0, stream>>>(Ure + 2*UST, Uim + 2*UST, B0, P);
  k_reduce<1><<<2048, 256, 0, stream>>>(P, B1);
  k_gemm<<<dim3(DIM/BN, KSPLIT), 256, 0, stream>>>(Ure + 3*UST, Uim + 3*UST, B1, P);
  k_reduce<2><<<2048, 256, 0, stream>>>(P, out);
}

// Round 2
// 209.756 us; speedup vs baseline: 3.0271x; 3.0271x over previous
//
#include <hip/hip_runtime.h>
#include <hip/hip_bf16.h>
#include <math.h>

#define N_WIRES 12
#define DIM     4096
#define BATCH   128
#define BD      (BATCH*DIM)
#define BM      128
#define BN      32
#define BK      64
#define KS      4
#define KCHUNK  (DIM / KS)

typedef __attribute__((ext_vector_type(4))) float f32x4;
typedef __attribute__((ext_vector_type(4))) unsigned int u32x4;
typedef __bf16 bf16x8 __attribute__((ext_vector_type(8)));
typedef __attribute__((ext_vector_type(8))) unsigned short us8;

__device__ __forceinline__ f32x4 mfma16(bf16x8 a, bf16x8 b, f32x4 c){
  return __builtin_amdgcn_mfma_f32_16x16x32_bf16(a, b, c, 0, 0, 0);
}

__device__ __forceinline__ void gload16(const void* g, void* l){
  __builtin_amdgcn_global_load_lds(
    (const __attribute__((address_space(1))) unsigned int*)g,
    (__attribute__((address_space(3))) unsigned int*)l, 16, 0, 0);
}

// Global state layout (bf16): [c][b][DIM], where within each 64-col block the
// 16B chunks are XOR-swizzled by (b&7): logical elem j of row b stored at
// (j & ~63) | ((((j>>3)&7) ^ (b&7)) << 3) | (j&7).  GEMM DMAs rows linearly
// into LDS and reads fragments with the same XOR -> bank-conflict-free.

// ---------------------------------------------------------------- normalize
__global__ void k_normalize(const float* __restrict__ x, __hip_bfloat16* __restrict__ dst){
  const int b = blockIdx.x, t = threadIdx.x;
  const float4* xr = reinterpret_cast<const float4*>(x + (size_t)b * DIM);
  float4 v[4];
  float ss = 0.f;
  #pragma unroll
  for (int r = 0; r < 4; ++r){
    v[r] = xr[t*4 + r];                    // elems t*16 + r*4 ..
    ss += v[r].x*v[r].x + v[r].y*v[r].y + v[r].z*v[r].z + v[r].w*v[r].w;
  }
  #pragma unroll
  for (int off = 32; off > 0; off >>= 1) ss += __shfl_down(ss, off);
  __shared__ float sred[4];
  if ((t & 63) == 0) sred[t >> 6] = ss;
  __syncthreads();
  const float inv = 1.f / sqrtf(sred[0] + sred[1] + sred[2] + sred[3]);
  #pragma unroll
  for (int h = 0; h < 2; ++h){
    union { __bf16 e[8]; us8 s; } pk;
    const float* vv = reinterpret_cast<const float*>(&v[h*2]);
    #pragma unroll
    for (int j = 0; j < 8; ++j) pk.e[j] = (__bf16)(vv[j] * inv);
    const int j0 = t*16 + h*8;
    const int sc = ((j0 >> 3) & 7) ^ (b & 7);
    *reinterpret_cast<us8*>(dst + (size_t)b*DIM + (j0 & ~63) + sc*8) = pk.s;
  }
}

// ---------------------------------------------------------------- complex GEMM
// C[b,n] = sum_k U[n,k] * X[b,k], K split into KS partials.
// X: swizzled bf16 state [2][BATCH][DIM] (CIN=false: real only, c0 plane).
// P: [KS][2][BATCH][DIM] f32.
template<bool CIN>
__global__ __launch_bounds__(256, 2) void k_gemm(
    const float* __restrict__ Ure, const float* __restrict__ Uim,
    const __hip_bfloat16* __restrict__ X, float* __restrict__ P)
{
  constexpr int NCC = CIN ? 2 : 1;
  __shared__ __bf16 Xs[NCC*BM*BK];     // 32 KB (16 KB real-only)
  __shared__ __bf16 Us[2*BN*BK];       // 8 KB
  const int t = threadIdx.x;
  const int lane = t & 63, wid = t >> 6;
  const int n0 = blockIdx.x * BN;
  const int kb = blockIdx.y * KCHUNK;

  const f32x4 z4 = {0.f,0.f,0.f,0.f};
  f32x4 acc[2][2][2];                  // [mi][ni][re/im]
  #pragma unroll
  for (int mi = 0; mi < 2; ++mi)
    #pragma unroll
    for (int ni = 0; ni < 2; ++ni){ acc[mi][ni][0] = z4; acc[mi][ni][1] = z4; }

  for (int kk = 0; kk < KCHUNK; kk += BK){
    __syncthreads();
    // ---- X tiles: zero-VGPR DMA, linear (swizzle lives in global layout)
    #pragma unroll
    for (int r = 0; r < NCC*4; ++r){
      const int idx = r*256 + t;                   // 16B-chunk id
      const int c   = idx >> 10;
      const int ci  = idx & 1023;
      const int row = ci >> 3, sc = ci & 7;
      const __hip_bfloat16* src = X + (size_t)c*BD + (size_t)row*DIM + (kb + kk) + sc*8;
      gload16(src, &Xs[idx*8]);
    }
    // ---- U tiles: 4 float4 batched loads -> cvt -> swizzled LDS write
    float4 uv[4];
    #pragma unroll
    for (int r = 0; r < 4; ++r){
      const int idx = r*256 + t;                   // 2c x 32rows x 16q
      const int c = idx >> 9, ci = idx & 511;
      const int row = ci >> 4, q = ci & 15;
      const float* us = c ? Uim : Ure;
      uv[r] = *reinterpret_cast<const float4*>(us + (size_t)(n0 + row)*DIM + (kb + kk) + q*4);
    }
    #pragma unroll
    for (int r = 0; r < 4; ++r){
      const int idx = r*256 + t;
      const int c = idx >> 9, ci = idx & 511;
      const int row = ci >> 4, q = ci & 15;
      union { __bf16 h[4]; unsigned long long u; } pk;
      pk.h[0]=(__bf16)uv[r].x; pk.h[1]=(__bf16)uv[r].y;
      pk.h[2]=(__bf16)uv[r].z; pk.h[3]=(__bf16)uv[r].w;
      const int e = (((q >> 1) ^ (row & 7)) << 3) | ((q & 1) << 2);
      *reinterpret_cast<unsigned long long*>(&Us[c*BN*BK + row*BK + e]) = pk.u;
    }
    __syncthreads();

    #pragma unroll
    for (int ks = 0; ks < 2; ++ks){
      const int lc = ks*4 + (lane >> 4);           // logical 16B chunk
      bf16x8 ar[2], ai[2], br[2], bi[2];
      #pragma unroll
      for (int mi = 0; mi < 2; ++mi){
        const int row = wid*32 + mi*16 + (lane & 15);
        const int off = row*BK + ((lc ^ (row & 7)) << 3);
        ar[mi] = *reinterpret_cast<const bf16x8*>(&Xs[off]);
        if (CIN) ai[mi] = *reinterpret_cast<const bf16x8*>(&Xs[BM*BK + off]);
      }
      #pragma unroll
      for (int ni = 0; ni < 2; ++ni){
        const int row = ni*16 + (lane & 15);
        const int off = row*BK + ((lc ^ (row & 7)) << 3);
        br[ni] = *reinterpret_cast<const bf16x8*>(&Us[off]);
        bi[ni] = *reinterpret_cast<const bf16x8*>(&Us[BN*BK + off]);
      }
      #pragma unroll
      for (int mi = 0; mi < 2; ++mi){
        bf16x8 an = ar[mi];
        if (CIN){
          const u32x4 negu = __builtin_bit_cast(u32x4, ai[mi]) ^ 0x80008000u;
          an = __builtin_bit_cast(bf16x8, negu);
        }
        #pragma unroll
        for (int ni = 0; ni < 2; ++ni){
          acc[mi][ni][0] = mfma16(ar[mi], br[ni], acc[mi][ni][0]);   // +Ure*Xre
          acc[mi][ni][1] = mfma16(ar[mi], bi[ni], acc[mi][ni][1]);   // +Uim*Xre
          if (CIN){
            acc[mi][ni][0] = mfma16(an,     bi[ni], acc[mi][ni][0]); // -Uim*Xim
            acc[mi][ni][1] = mfma16(ai[mi], br[ni], acc[mi][ni][1]); // +Ure*Xim
          }
        }
      }
    }
  }
  float* pre = P + (size_t)(blockIdx.y*2 + 0)*BD;
  float* pim = P + (size_t)(blockIdx.y*2 + 1)*BD;
  #pragma unroll
  for (int mi = 0; mi < 2; ++mi)
    #pragma unroll
    for (int ni = 0; ni < 2; ++ni){
      const int col = n0 + ni*16 + (lane & 15);
      const int m0 = wid*32 + mi*16 + (lane >> 4)*4;
      #pragma unroll
      for (int j = 0; j < 4; ++j){
        pre[(size_t)(m0+j)*DIM + col] = acc[mi][ni][0][j];
        pim[(size_t)(m0+j)*DIM + col] = acc[mi][ni][1][j];
      }
    }
}

// ------------------------------------------------- CNOT ring, forward map
// new[dst(m)] = old[m]; dst = gates applied in order i=0..11.
__device__ __forceinline__ int cnot_dst(int x){
  #pragma unroll
  for (int i = 0; i < 12; ++i){
    const int cb = 11 - i;
    const int tb = 11 - ((i + 1) % 12);
    x ^= ((x >> cb) & 1) << tb;
  }
  return x;
}

// ----------------------------------- reduce + CNOT permute -> bf16 swz state
__global__ void k_perm(const float* __restrict__ P, __hip_bfloat16* __restrict__ dst){
  const int idx = blockIdx.x * 256 + threadIdx.x;
  const int b = idx >> 12;
  const int m = idx & (DIM - 1);
  float re = 0.f, im = 0.f;
  #pragma unroll
  for (int s = 0; s < KS; ++s){
    re += P[(size_t)(s*2+0)*BD + (size_t)b*DIM + m];
    im += P[(size_t)(s*2+1)*BD + (size_t)b*DIM + m];
  }
  const int k = cnot_dst(m);
  const int e = (k & ~63) | (((((k >> 3) & 7) ^ (b & 7)) << 3)) | (k & 7);
  dst[(size_t)b*DIM + e] = __float2bfloat16(re);
  dst[(size_t)BD + (size_t)b*DIM + e] = __float2bfloat16(im);
}

// ----------------------------------------------- reduce + abs -> output f32
__global__ void k_abs(const float* __restrict__ P, float* __restrict__ dst){
  const int idx = blockIdx.x * 256 + threadIdx.x;
  const int b = idx >> 12;
  const int m = idx & (DIM - 1);
  float re = 0.f, im = 0.f;
  #pragma unroll
  for (int s = 0; s < KS; ++s){
    re += P[(size_t)(s*2+0)*BD + (size_t)b*DIM + m];
    im += P[(size_t)(s*2+1)*BD + (size_t)b*DIM + m];
  }
  dst[idx] = sqrtf(re*re + im*im);
}

// ---------------------------------------------------------------- QFT
__global__ void k_qft(const float* __restrict__ P, __hip_bfloat16* __restrict__ out){
  __shared__ float sre[DIM];
  __shared__ float sim[DIM];
  const int b = blockIdx.x, t = threadIdx.x;
  for (int i = t; i < DIM; i += 512){
    float re = 0.f, im = 0.f;
    #pragma unroll
    for (int s = 0; s < KS; ++s){
      re += P[(size_t)(s*2+0)*BD + (size_t)b*DIM + i];
      im += P[(size_t)(s*2+1)*BD + (size_t)b*DIM + i];
    }
    sre[i] = re; sim[i] = im;
  }
  __syncthreads();
  const float rs2 = 0.70710678118654752440f;
  for (int m = 11; m >= 1; --m){
    const int p = 11 - m;
    const int mask = 1 << p;
    for (int q = t; q < 2048; q += 512){
      const int i0 = ((q & ~(mask-1)) << 1) | (q & (mask-1));
      const int i1 = i0 | mask;
      const float r0 = sre[i0], s0 = sim[i0], r1 = sre[i1], s1 = sim[i1];
      sre[i0] = (r0 + r1) * rs2; sim[i0] = (s0 + s1) * rs2;
      sre[i1] = (r0 - r1) * rs2; sim[i1] = (s0 - s1) * rs2;
    }
    __syncthreads();
    for (int q = t; q < 2048; q += 512){
      const int i1 = (((q & ~(mask-1)) << 1) | (q & (mask-1))) | mask;
      int u = i1 >> (p + 1);
      float phi = 0.f, w = 1.57079632679489662f;
      while (u){ if (u & 1) phi += w; w *= 0.5f; u >>= 1; }
      float cc, ss;
      __sincosf(phi, &ss, &cc);
      const float r = sre[i1], q2 = sim[i1];
      sre[i1] = r*cc - q2*ss;
      sim[i1] = r*ss + q2*cc;
    }
    __syncthreads();
  }
  for (int i = t; i < DIM; i += 512){
    const int rsrc = (int)(__brev((unsigned)i) >> 20);
    const int e = (i & ~63) | (((((i >> 3) & 7) ^ (b & 7)) << 3)) | (i & 7);
    out[(size_t)b*DIM + e] = __float2bfloat16(sre[rsrc]);
    out[(size_t)BD + (size_t)b*DIM + e] = __float2bfloat16(sim[rsrc]);
  }
}

// ---------------------------------------------------------------- launch
extern "C" void kernel_launch(void* const* d_in, const int* in_sizes, int n_in,
                              void* d_out, int out_size, void* d_ws, size_t ws_size,
                              hipStream_t stream){
  const float* x   = (const float*)d_in[0];
  const float* Ure = (const float*)d_in[1];   // [4][DIM][DIM]
  const float* Uim = (const float*)d_in[2];
  float* out = (float*)d_out;

  float* P = (float*)d_ws;                                   // 16.8 MB partials
  __hip_bfloat16* B0 = (__hip_bfloat16*)(P + (size_t)KS*2*BD);  // 2 MB state
  __hip_bfloat16* B1 = B0 + (size_t)2*BD;                       // 2 MB state
  const size_t UST = (size_t)DIM*DIM;
  const dim3 gg(DIM/BN, KS);

  k_normalize<<<BATCH, 256, 0, stream>>>(x, B0);
  // vqc(0): U0, CNOT ring, U1
  k_gemm<false><<<gg, 256, 0, stream>>>(Ure, Uim, B0, P);
  k_perm<<<BD/256, 256, 0, stream>>>(P, B1);
  k_gemm<true><<<gg, 256, 0, stream>>>(Ure + UST, Uim + UST, B1, P);
  // qft (consumes partials, writes B0)
  k_qft<<<BATCH, 512, 0, stream>>>(P, B0);
  // vqc(1): U2, CNOT ring, U3
  k_gemm<true><<<gg, 256, 0, stream>>>(Ure + 2*UST, Uim + 2*UST, B0, P);
  k_perm<<<BD/256, 256, 0, stream>>>(P, B1);
  k_gemm<true><<<gg, 256, 0, stream>>>(Ure + 3*UST, Uim + 3*UST, B1, P);
  k_abs<<<BD/256, 256, 0, stream>>>(P, out);
}